// Round 1
// baseline (362.528 us; speedup 1.0000x reference)
//
#include <hip/hip_runtime.h>
#include <math.h>
#include <stdint.h>

#define B_ 8
#define T_ 256
#define N_ 128
#define K_ 64

// ---------------- Kernel 1: log-emission (log-softmax of obs @ W + b) ----------------
__global__ __launch_bounds__(128) void k_emit(
    const float* __restrict__ obs,    // [B,T,K]
    const int*   __restrict__ dur,    // [B]
    const float* __restrict__ W,      // [K,N]
    const float* __restrict__ bias,   // [N]
    float* __restrict__ le)           // [B,T,N]
{
    int bt = blockIdx.x;              // b*T + t
    int b  = bt >> 8;                 // T_ = 256
    int t  = bt & 255;
    if (t >= dur[b]) return;          // only t < duration[b] is ever consumed
    int n = threadIdx.x;              // 0..127
    __shared__ float o[K_];
    __shared__ float wmax[2];
    __shared__ float wsum[2];
    if (n < K_) o[n] = obs[(size_t)bt * K_ + n];
    __syncthreads();
    float acc = bias[n];
    #pragma unroll
    for (int k = 0; k < K_; ++k)
        acc = fmaf(o[k], W[k * N_ + n], acc);
    // logsumexp over 128 threads (2 waves)
    float m = acc;
    #pragma unroll
    for (int off = 32; off; off >>= 1) m = fmaxf(m, __shfl_xor(m, off));
    int w = n >> 6;
    if ((n & 63) == 0) wmax[w] = m;
    __syncthreads();
    float M = fmaxf(wmax[0], wmax[1]);
    float e = expf(acc - M);
    float s = e;
    #pragma unroll
    for (int off = 32; off; off >>= 1) s += __shfl_xor(s, off);
    if ((n & 63) == 0) wsum[w] = s;
    __syncthreads();
    float S = wsum[0] + wsum[1];
    le[(size_t)bt * N_ + n] = acc - M - logf(S);
}

// ---------------- Kernel 2: reciprocal row L1 sums of transition ----------------
__global__ __launch_bounds__(256) void k_invl1(
    const float* __restrict__ trans,  // [T,B,N,N]
    const int*   __restrict__ dur,    // [B]
    float* __restrict__ invl1)        // [T,B,N]  indexed (t*B+b)*N+k
{
    int tb = blockIdx.x;              // t*B + b
    int b  = tb & 7;
    int t  = tb >> 3;
    if (t >= dur[b]) return;
    int tid = threadIdx.x;            // 0..255
    const float4* tp = (const float4*)(trans + (size_t)tb * (N_ * N_));
    __shared__ float part[N_][33];    // +1 pad breaks bank conflicts on the reduce
    #pragma unroll
    for (int i = 0; i < 16; ++i) {
        int f = tid + (i << 8);       // float4 index 0..4095 (coalesced per iteration)
        float4 v = tp[f];
        int row = f >> 5;             // 32 float4 per row
        part[row][tid & 31] = v.x + v.y + v.z + v.w;   // (row, tid&31) bijective
    }
    __syncthreads();
    if (tid < N_) {
        float ssum = 0.f;
        #pragma unroll
        for (int c = 0; c < 32; ++c) ssum += part[tid][c];
        invl1[(size_t)tb * N_ + tid] = 1.0f / ssum;    // transitions strictly > 0
    }
}

// ---------------- Kernel 3: serial forward recursion, one block per batch ----------------
// Per step (exact rewrite of the reference log-domain recursion):
//   M = max_k la[k]
//   pp[k] = exp(la[k]-M) * invl1[t,b,k]
//   s[j]  = sum_k pp[k] * trans[t,b,k,j]
//   la[j] = le[b,t,j] + M + log(s[j])
__global__ __launch_bounds__(512, 1) void k_forward(
    const float* __restrict__ trans,  // [T,B,N,N]
    const int*   __restrict__ dur,    // [B]
    const float* __restrict__ sp,     // [B,N]
    const float* __restrict__ le,     // [B,T,N]
    const float* __restrict__ invl1,  // [T,B,N]
    float* __restrict__ out)          // [B]
{
    const int b    = blockIdx.x;
    const int tid  = threadIdx.x;     // 0..511
    const int lane = tid & 63;
    const int jq   = tid & 31;        // j-quad 0..31  (covers j = jq*4 .. jq*4+3)
    const int g    = tid >> 5;        // k-group 0..15 (covers k = g*8 .. g*8+7)

    __shared__ float tile[2][N_ * N_];  // 2 x 64 KB double buffer
    __shared__ float la[N_];
    __shared__ float pp[N_];
    __shared__ float part[16][N_];

    const int d = dur[b];

    // la0 = le[b,0,:] + log(start_prob[b,:])
    if (tid < N_) la[tid] = le[((size_t)b * T_) * N_ + tid] + logf(sp[b * N_ + tid]);

    // prefetch tile for t=1 into registers
    float4 rg0, rg1, rg2, rg3, rg4, rg5, rg6, rg7;
    if (d > 1) {
        const float4* gp = (const float4*)(trans + ((size_t)(1 * B_ + b)) * (N_ * N_));
        rg0 = gp[tid];           rg1 = gp[tid + 512];
        rg2 = gp[tid + 1024];    rg3 = gp[tid + 1536];
        rg4 = gp[tid + 2048];    rg5 = gp[tid + 2560];
        rg6 = gp[tid + 3072];    rg7 = gp[tid + 3584];
    }
    __syncthreads();
    if (d > 1) {
        float4* lt = (float4*)tile[0];
        lt[tid]        = rg0;  lt[tid + 512]  = rg1;
        lt[tid + 1024] = rg2;  lt[tid + 1536] = rg3;
        lt[tid + 2048] = rg4;  lt[tid + 2560] = rg5;
        lt[tid + 3072] = rg6;  lt[tid + 3584] = rg7;
    }
    __syncthreads();

    int cur = 0;
    for (int t = 1; t < d; ++t) {
        // ---- phase a: issue next-tile loads + per-row le/invl1 loads; wave-local max over la
        float le_t = 0.f, inv_t = 0.f;
        if (tid < N_) {
            le_t  = le[((size_t)b * T_ + t) * N_ + tid];
            inv_t = invl1[((size_t)t * B_ + b) * N_ + tid];
        }
        if (t + 1 < d) {
            const float4* gp = (const float4*)(trans + ((size_t)(t + 1) * B_ + b) * (N_ * N_));
            rg0 = gp[tid];           rg1 = gp[tid + 512];
            rg2 = gp[tid + 1024];    rg3 = gp[tid + 1536];
            rg4 = gp[tid + 2048];    rg5 = gp[tid + 2560];
            rg6 = gp[tid + 3072];    rg7 = gp[tid + 3584];
        }
        float v = fmaxf(la[lane], la[lane + 64]);
        #pragma unroll
        for (int off = 32; off; off >>= 1) v = fmaxf(v, __shfl_xor(v, off));
        const float M = v;

        // ---- phase b: scaled probabilities (la unchanged since last step's barrier)
        if (tid < N_) pp[tid] = expf(la[tid] - M) * inv_t;
        __syncthreads();                       // pp ready

        // ---- phase c: matvec  part[g][j] = sum_{k in group g} pp[k]*tile[k][j]
        const float4* t4 = (const float4*)tile[cur];
        float sx = 0.f, sy = 0.f, sz = 0.f, sw = 0.f;
        #pragma unroll
        for (int kk = 0; kk < 8; ++kk) {
            int k = (g << 3) + kk;
            float4 tv = t4[(k << 5) + jq];     // full row across 32 lanes: conflict-free
            float pk = pp[k];                  // broadcast
            sx = fmaf(pk, tv.x, sx);
            sy = fmaf(pk, tv.y, sy);
            sz = fmaf(pk, tv.z, sz);
            sw = fmaf(pk, tv.w, sw);
        }
        {
            float4* p4 = (float4*)part;
            float4 o4; o4.x = sx; o4.y = sy; o4.z = sz; o4.w = sw;
            p4[(g << 5) + jq] = o4;
        }
        __syncthreads();                       // part ready, tile[cur] free

        // ---- phase d: combine + log, write new la; write prefetched tile
        if (tid < N_) {
            float s = 0.f;
            #pragma unroll
            for (int gg = 0; gg < 16; ++gg) s += part[gg][tid];
            la[tid] = le_t + M + logf(s);
        }
        if (t + 1 < d) {
            float4* lt = (float4*)tile[cur ^ 1];
            lt[tid]        = rg0;  lt[tid + 512]  = rg1;
            lt[tid + 1024] = rg2;  lt[tid + 1536] = rg3;
            lt[tid + 2048] = rg4;  lt[tid + 2560] = rg5;
            lt[tid + 3072] = rg6;  lt[tid + 3584] = rg7;
        }
        __syncthreads();                       // la + next tile ready
        cur ^= 1;
    }

    // ---- final: out[b] = logsumexp_j la[j]  (la corresponds to t = d-1)
    if (tid < 64) {
        float v0 = la[tid], v1 = la[tid + 64];
        float m = fmaxf(v0, v1);
        #pragma unroll
        for (int off = 32; off; off >>= 1) m = fmaxf(m, __shfl_xor(m, off));
        float s = expf(v0 - m) + expf(v1 - m);
        #pragma unroll
        for (int off = 32; off; off >>= 1) s += __shfl_xor(s, off);
        if (tid == 0) out[b] = m + logf(s);
    }
}

extern "C" void kernel_launch(void* const* d_in, const int* in_sizes, int n_in,
                              void* d_out, int out_size, void* d_ws, size_t ws_size,
                              hipStream_t stream) {
    const float* obs   = (const float*)d_in[0];   // [B,T,K]
    const int*   dur   = (const int*)  d_in[1];   // [B]
    const float* trans = (const float*)d_in[2];   // [T,B,N,N]
    const float* sp    = (const float*)d_in[3];   // [B,N]
    const float* W     = (const float*)d_in[4];   // [K,N]
    const float* bias  = (const float*)d_in[5];   // [N]
    float* out = (float*)d_out;                   // [B,1] -> 8 floats

    float* le    = (float*)d_ws;                               // B*T*N floats = 1 MB
    float* invl1 = le + (size_t)B_ * T_ * N_;                  // T*B*N floats = 1 MB

    hipLaunchKernelGGL(k_emit,  dim3(B_ * T_), dim3(128), 0, stream, obs, dur, W, bias, le);
    hipLaunchKernelGGL(k_invl1, dim3(T_ * B_), dim3(256), 0, stream, trans, dur, invl1);
    hipLaunchKernelGGL(k_forward, dim3(B_), dim3(512), 0, stream,
                       trans, dur, sp, le, invl1, out);
}

// Round 2
// 289.213 us; speedup vs baseline: 1.2535x; 1.2535x over previous
//
#include <hip/hip_runtime.h>
#include <math.h>
#include <stdint.h>

#define B_ 8
#define T_ 256
#define N_ 128
#define K_ 64

// ---------------- Kernel 1: log-emission (log-softmax of obs @ W + b) ----------------
__global__ __launch_bounds__(128) void k_emit(
    const float* __restrict__ obs,    // [B,T,K]
    const int*   __restrict__ dur,    // [B]
    const float* __restrict__ W,      // [K,N]
    const float* __restrict__ bias,   // [N]
    float* __restrict__ le)           // [B,T,N]
{
    int bt = blockIdx.x;              // b*T + t
    int b  = bt >> 8;                 // T_ = 256
    int t  = bt & 255;
    if (t >= dur[b]) return;          // only t < duration[b] is ever consumed
    int n = threadIdx.x;              // 0..127
    __shared__ float o[K_];
    __shared__ float wmax[2];
    __shared__ float wsum[2];
    if (n < K_) o[n] = obs[(size_t)bt * K_ + n];
    __syncthreads();
    float acc = bias[n];
    #pragma unroll
    for (int k = 0; k < K_; ++k)
        acc = fmaf(o[k], W[k * N_ + n], acc);
    float m = acc;
    #pragma unroll
    for (int off = 32; off; off >>= 1) m = fmaxf(m, __shfl_xor(m, off));
    int w = n >> 6;
    if ((n & 63) == 0) wmax[w] = m;
    __syncthreads();
    float M = fmaxf(wmax[0], wmax[1]);
    float e = expf(acc - M);
    float s = e;
    #pragma unroll
    for (int off = 32; off; off >>= 1) s += __shfl_xor(s, off);
    if ((n & 63) == 0) wsum[w] = s;
    __syncthreads();
    float S = wsum[0] + wsum[1];
    le[(size_t)bt * N_ + n] = acc - M - logf(S);
}

// ---------------- Kernel 2: reciprocal row L1 sums of transition ----------------
__global__ __launch_bounds__(256) void k_invl1(
    const float* __restrict__ trans,  // [T,B,N,N]
    const int*   __restrict__ dur,    // [B]
    float* __restrict__ invl1)        // [T,B,N]  indexed (t*B+b)*N+k
{
    int tb = blockIdx.x;              // t*B + b
    int b  = tb & 7;
    int t  = tb >> 3;
    if (t >= dur[b]) return;
    int tid = threadIdx.x;            // 0..255
    const float4* tp = (const float4*)(trans + (size_t)tb * (N_ * N_));
    __shared__ float part[N_][33];
    #pragma unroll
    for (int i = 0; i < 16; ++i) {
        int f = tid + (i << 8);
        float4 v = tp[f];
        int row = f >> 5;
        part[row][tid & 31] = v.x + v.y + v.z + v.w;
    }
    __syncthreads();
    if (tid < N_) {
        float ssum = 0.f;
        #pragma unroll
        for (int c = 0; c < 32; ++c) ssum += part[tid][c];
        invl1[(size_t)tb * N_ + tid] = 1.0f / ssum;
    }
}

// ---------------- Kernel 3: serial forward recursion ----------------
// Register-resident tiles (depth-2 prefetch, 3-buffer rotation), 2 raw barriers
// per step with lgkm-only drain (global prefetch stays in flight), lagged global
// max M̂ (exact: M factors out of le + M + log s for any M).
//
// Thread layout (512 thr): g = tid>>5 owns tile rows k=8g..8g+7; jq = tid&31 owns
// cols 4jq..4jq+3. Wave w owns states j in [16w,16w+16) for the combine phase
// (which is exactly the k-range it needs for next step's pp -> no cross-wave pp).

#define BAR() { asm volatile("s_waitcnt lgkmcnt(0)" ::: "memory"); __builtin_amdgcn_s_barrier(); }

#define LOADTILE(BUF, tt) { \
    const float4* gp_ = (const float4*)(trans + (((size_t)(tt) * B_ + b) << 14)); \
    BUF[0] = gp_[tb4];        BUF[1] = gp_[tb4 + 32]; \
    BUF[2] = gp_[tb4 + 64];   BUF[3] = gp_[tb4 + 96]; \
    BUF[4] = gp_[tb4 + 128];  BUF[5] = gp_[tb4 + 160]; \
    BUF[6] = gp_[tb4 + 192];  BUF[7] = gp_[tb4 + 224]; }

#define FMA4(PK, V) { sx = fmaf(PK, V.x, sx); sy = fmaf(PK, V.y, sy); \
                      sz = fmaf(PK, V.z, sz); sw = fmaf(PK, V.w, sw); }

#define STEP(tt, USE, FILL) { \
    const int t_ = (tt); \
    /* ---- B phase: issue prefetch t+2, le/inv for next step; matvec from regs */ \
    if (t_ + 2 < d) LOADTILE(FILL, t_ + 2); \
    int tl_ = (t_ + 1 < d) ? t_ + 1 : d - 1; \
    float leN_ = le[((size_t)b * T_ + tl_) * N_ + jrow]; \
    int ti_ = (t_ + 2 < d) ? t_ + 2 : d - 1; \
    float invN_ = invl1[((size_t)ti_ * B_ + b) * N_ + jrow]; \
    float sx = 0.f, sy = 0.f, sz = 0.f, sw = 0.f; \
    FMA4(ppq0.x, USE[0]); FMA4(ppq0.y, USE[1]); \
    FMA4(ppq0.z, USE[2]); FMA4(ppq0.w, USE[3]); \
    FMA4(ppq1.x, USE[4]); FMA4(ppq1.y, USE[5]); \
    FMA4(ppq1.z, USE[6]); FMA4(ppq1.w, USE[7]); \
    *(float4*)&part[g][jq << 2] = make_float4(sx, sy, sz, sw); \
    BAR(); \
    /* ---- C phase: combine, la update, next pp with lagged global max */ \
    float p0_ = part[(q << 2) + 0][jrow] + part[(q << 2) + 1][jrow] \
              + part[(q << 2) + 2][jrow] + part[(q << 2) + 3][jrow]; \
    p0_ += __shfl_xor(p0_, 16); \
    p0_ += __shfl_xor(p0_, 32); \
    laR = leC + Mpp + __logf(p0_); \
    float m_ = laR; \
    m_ = fmaxf(m_, __shfl_xor(m_, 1)); \
    m_ = fmaxf(m_, __shfl_xor(m_, 2)); \
    m_ = fmaxf(m_, __shfl_xor(m_, 4)); \
    m_ = fmaxf(m_, __shfl_xor(m_, 8)); \
    float4 wa_ = *(const float4*)&wmb[t_ & 1][0]; \
    float4 wb_ = *(const float4*)&wmb[t_ & 1][4]; \
    float Mh_ = fmaxf(fmaxf(fmaxf(wa_.x, wa_.y), fmaxf(wa_.z, wa_.w)), \
                      fmaxf(fmaxf(wb_.x, wb_.y), fmaxf(wb_.z, wb_.w))); \
    if (lane == 0) wmb[(t_ + 1) & 1][wv] = m_; \
    float ppv_ = __expf(laR - Mh_) * invC; \
    if (lane < 16) ppl[jrow] = ppv_; \
    ppq0 = pp4[2 * g]; \
    ppq1 = pp4[2 * g + 1]; \
    Mpp = Mh_; leC = leN_; invC = invN_; \
    BAR(); \
}

__global__ __launch_bounds__(512, 1) void k_forward(
    const float* __restrict__ trans,  // [T,B,N,N]
    const int*   __restrict__ dur,    // [B]
    const float* __restrict__ sp,     // [B,N]
    const float* __restrict__ le,     // [B,T,N]
    const float* __restrict__ invl1,  // [T,B,N]
    float* __restrict__ out)          // [B]
{
    const int b    = blockIdx.x;
    const int tid  = threadIdx.x;
    const int lane = tid & 63;
    const int wv   = tid >> 6;        // wave 0..7
    const int g    = tid >> 5;        // k-group 0..15
    const int jq   = tid & 31;        // j-quad 0..31
    const int r    = lane & 15;
    const int q    = lane >> 4;       // 0..3
    const int jrow = (wv << 4) + r;   // state this lane owns in C phase
    const int tb4  = (g << 8) + jq;   // tile float4 base for this thread

    __shared__ __align__(16) float part[16][132];  // stride 132: aligned f4, ~2-way reads
    __shared__ __align__(16) float ppl[N_];
    __shared__ __align__(16) float wmb[2][8];      // double-buffered per-wave maxima
    __shared__ __align__(16) float la_f[N_];

    const int d = dur[b];
    const float4* pp4 = (const float4*)ppl;

    float4 bufA[8], bufB[8], bufC[8];
    float4 ppq0, ppq1;
    float laR, Mpp, leC, invC;

    // issue tile prefetches for t=1,2 ASAP (overlap bootstrap)
    if (d > 1) LOADTILE(bufA, 1);
    if (d > 2) LOADTILE(bufB, 2);

    // ---- bootstrap (t = 0) ----
    {
        float le0 = le[((size_t)b * T_) * N_ + jrow];
        float lsp = __logf(sp[b * N_ + jrow]);
        laR = le0 + lsp;
        float m = laR;
        m = fmaxf(m, __shfl_xor(m, 1));
        m = fmaxf(m, __shfl_xor(m, 2));
        m = fmaxf(m, __shfl_xor(m, 4));
        m = fmaxf(m, __shfl_xor(m, 8));
        if (lane == 0) wmb[1][wv] = m;
        BAR();
        float4 wa = *(const float4*)&wmb[1][0];
        float4 wb = *(const float4*)&wmb[1][4];
        float Mh = fmaxf(fmaxf(fmaxf(wa.x, wa.y), fmaxf(wa.z, wa.w)),
                         fmaxf(fmaxf(wb.x, wb.y), fmaxf(wb.z, wb.w)));
        Mpp = Mh;
        int t1 = (d > 1) ? 1 : 0;
        float inv1 = invl1[((size_t)t1 * B_ + b) * N_ + jrow];
        float ppv = __expf(laR - Mh) * inv1;
        if (lane < 16) ppl[jrow] = ppv;
        ppq0 = pp4[2 * g];            // same-wave LDS order: sees the write above
        ppq1 = pp4[2 * g + 1];
        leC  = le[((size_t)b * T_ + t1) * N_ + jrow];           // le[t=1]
        int ti = (d > 2) ? 2 : d - 1;
        invC = invl1[((size_t)ti * B_ + b) * N_ + jrow];        // inv[t=2]
        // no barrier needed: wmb[1] stays valid for C(1); pp read is same-wave
    }

    // ---- main loop: tile(t) lives in buf[(t-1)%3] ----
    int t = 1;
    for (; t + 2 < d; t += 3) {
        STEP(t,     bufA, bufC);
        STEP(t + 1, bufB, bufA);
        STEP(t + 2, bufC, bufB);
    }
    if (t < d) { STEP(t, bufA, bufC); ++t; }
    if (t < d) { STEP(t, bufB, bufA); ++t; }

    // ---- final: out[b] = logsumexp_j la[j] at t = d-1 ----
    if (lane < 16) la_f[jrow] = laR;
    BAR();
    if (tid < 64) {
        float v0 = la_f[tid], v1 = la_f[tid + 64];
        float m = fmaxf(v0, v1);
        #pragma unroll
        for (int off = 32; off; off >>= 1) m = fmaxf(m, __shfl_xor(m, off));
        float s = __expf(v0 - m) + __expf(v1 - m);
        #pragma unroll
        for (int off = 32; off; off >>= 1) s += __shfl_xor(s, off);
        if (tid == 0) out[b] = m + __logf(s);
    }
}

extern "C" void kernel_launch(void* const* d_in, const int* in_sizes, int n_in,
                              void* d_out, int out_size, void* d_ws, size_t ws_size,
                              hipStream_t stream) {
    const float* obs   = (const float*)d_in[0];   // [B,T,K]
    const int*   dur   = (const int*)  d_in[1];   // [B]
    const float* trans = (const float*)d_in[2];   // [T,B,N,N]
    const float* sp    = (const float*)d_in[3];   // [B,N]
    const float* W     = (const float*)d_in[4];   // [K,N]
    const float* bias  = (const float*)d_in[5];   // [N]
    float* out = (float*)d_out;

    float* le    = (float*)d_ws;                               // B*T*N = 1 MB
    float* invl1 = le + (size_t)B_ * T_ * N_;                  // T*B*N = 1 MB

    hipLaunchKernelGGL(k_emit,  dim3(B_ * T_), dim3(128), 0, stream, obs, dur, W, bias, le);
    hipLaunchKernelGGL(k_invl1, dim3(T_ * B_), dim3(256), 0, stream, trans, dur, invl1);
    hipLaunchKernelGGL(k_forward, dim3(B_), dim3(512), 0, stream,
                       trans, dur, sp, le, invl1, out);
}